// Round 1
// baseline (700.557 us; speedup 1.0000x reference)
//
#include <hip/hip_runtime.h>

#define BB 32
#define HH 384
#define WW 1280
#define KS 9
#define PADK 4

// ---------------------------------------------------------------------------
// Transpose x[B,H,W] -> xT[B,W,H] (into workspace) so the scan's per-column
// reads are coalesced. Standard 32x32 LDS tile transpose.
// ---------------------------------------------------------------------------
__global__ __launch_bounds__(256) void scnn_transpose(const float* __restrict__ x,
                                                      float* __restrict__ xT) {
    __shared__ float tile[32][33];
    const int b = blockIdx.z;
    const int w0 = blockIdx.x * 32;
    const int h0 = blockIdx.y * 32;
    const int tx = threadIdx.x;   // 0..31
    const int ty = threadIdx.y;   // 0..7
    const float* xb = x + (size_t)b * HH * WW;
    float* xTb = xT + (size_t)b * WW * HH;
#pragma unroll
    for (int i = 0; i < 32; i += 8) {
        tile[ty + i][tx] = xb[(size_t)(h0 + ty + i) * WW + (w0 + tx)];
    }
    __syncthreads();
#pragma unroll
    for (int i = 0; i < 32; i += 8) {
        xTb[(size_t)(w0 + ty + i) * HH + (h0 + tx)] = tile[tx][ty + i];
    }
}

// ---------------------------------------------------------------------------
// Fused bidirectional scan. One block per batch (b), one thread per h.
// Pass 1 (L->R): out1[w] = x[w] + relu(conv9(out1[w-1], w_lr)), in-place in xT.
// Pass 2 (R->L): out2[w] = out1[w] + relu(conv9(out2[w+1], w_rl)), -> d_out.
// Double-buffered LDS column => one barrier per step. Next input column is
// prefetched across the barrier.
// ---------------------------------------------------------------------------
__global__ __launch_bounds__(HH) void scnn_scan(float* __restrict__ xT,
                                                float* __restrict__ out,
                                                const float* __restrict__ w_lr,
                                                const float* __restrict__ w_rl) {
    __shared__ float buf[2][HH + 2 * PADK];
    const int b = blockIdx.x;
    const int h = threadIdx.x;
    float* base = xT + (size_t)b * WW * HH;
    float* outb = out + ((size_t)b * HH + h) * WW;

    float wl[KS], wr[KS];
#pragma unroll
    for (int k = 0; k < KS; ++k) { wl[k] = w_lr[k]; wr[k] = w_rl[k]; }

    // zero halos of both buffers once
    if (h < PADK) {
        buf[0][h] = 0.f;
        buf[1][h] = 0.f;
        buf[0][HH + PADK + h] = 0.f;
        buf[1][HH + PADK + h] = 0.f;
    }

    // ---- pass 1 (left -> right), output in-place into base ----
    float v = base[h];                 // out1 column 0 == x column 0
    buf[0][PADK + h] = v;
    float xv = base[HH + h];           // prefetch column 1
    int p = 0;
    __syncthreads();

    for (int w = 1; w < WW; ++w) {
        const int wn = (w + 1 < WW) ? (w + 1) : (WW - 1);
        const float xn = base[(size_t)wn * HH + h];   // prefetch next column
        float acc = 0.f;
#pragma unroll
        for (int k = 0; k < KS; ++k) acc = fmaf(wl[k], buf[p][h + k], acc);
        v = xv + fmaxf(acc, 0.f);
        buf[p ^ 1][PADK + h] = v;
        base[(size_t)w * HH + h] = v;                 // pass-1 output (in place)
        xv = xn;
        p ^= 1;
        __syncthreads();
    }

    // ---- pass 2 (right -> left), output straight to d_out [B,H,W] ----
    // buf[p] holds out1[W-1] == out2[W-1]; v holds this thread's element.
    outb[WW - 1] = v;
    xv = base[(size_t)(WW - 2) * HH + h];             // out1 column W-2
    for (int w = WW - 2; w >= 0; --w) {
        const int wn = (w > 0) ? (w - 1) : 0;
        const float xn = base[(size_t)wn * HH + h];   // prefetch next column
        float acc = 0.f;
#pragma unroll
        for (int k = 0; k < KS; ++k) acc = fmaf(wr[k], buf[p][h + k], acc);
        v = xv + fmaxf(acc, 0.f);
        buf[p ^ 1][PADK + h] = v;
        outb[w] = v;                                  // final output (scattered 4B)
        xv = xn;
        p ^= 1;
        __syncthreads();
    }
}

extern "C" void kernel_launch(void* const* d_in, const int* in_sizes, int n_in,
                              void* d_out, int out_size, void* d_ws, size_t ws_size,
                              hipStream_t stream) {
    const float* x    = (const float*)d_in[0];
    const float* w_lr = (const float*)d_in[1];
    const float* w_rl = (const float*)d_in[2];
    float* out = (float*)d_out;
    float* xT  = (float*)d_ws;   // B*W*H floats = 62.9 MB

    dim3 tb(32, 8);
    dim3 tg(WW / 32, HH / 32, BB);
    scnn_transpose<<<tg, tb, 0, stream>>>(x, xT);
    scnn_scan<<<BB, HH, 0, stream>>>(xT, out, w_lr, w_rl);
}

// Round 2
// 603.712 us; speedup vs baseline: 1.1604x; 1.1604x over previous
//
#include <hip/hip_runtime.h>

#define BB 32
#define HH 384
#define WW 1280
#define KS 9
#define NL 64     // lanes per wave
#define EPL 6     // H elements per lane (384/64)

// DPP wave shifts: cross-lane neighbor exchange at VALU latency, with
// bound_ctrl=true zero-filling the invalid edge lane (free zero padding).
__device__ __forceinline__ float dpp_up1(float x) {   // lane i <- lane i-1; lane 0 <- 0
    return __int_as_float(__builtin_amdgcn_mov_dpp(__float_as_int(x), 0x138, 0xf, 0xf, true));
}
__device__ __forceinline__ float dpp_dn1(float x) {   // lane i <- lane i+1; lane 63 <- 0
    return __int_as_float(__builtin_amdgcn_mov_dpp(__float_as_int(x), 0x130, 0xf, 0xf, true));
}

// 9-tap correlation along H of the register-resident column v (lane l holds
// h = l*6+j), zero-padded, then ReLU. a[j] = relu(sum_k wk[k]*p[h-4+k]).
__device__ __forceinline__ void conv9_relu(const float (&v)[EPL], const float (&wk)[KS],
                                           float (&a)[EPL]) {
    float n[EPL + 8];
    n[0]  = dpp_up1(v[2]);
    n[1]  = dpp_up1(v[3]);
    n[2]  = dpp_up1(v[4]);
    n[3]  = dpp_up1(v[5]);
#pragma unroll
    for (int j = 0; j < EPL; ++j) n[4 + j] = v[j];
    n[10] = dpp_dn1(v[0]);
    n[11] = dpp_dn1(v[1]);
    n[12] = dpp_dn1(v[2]);
    n[13] = dpp_dn1(v[3]);
#pragma unroll
    for (int j = 0; j < EPL; ++j) {
        float acc = wk[0] * n[j];
#pragma unroll
        for (int k = 1; k < KS; ++k) acc = fmaf(wk[k], n[j + k], acc);
        a[j] = fmaxf(acc, 0.f);
    }
}

// Load 4 consecutive x columns [4g..4g+4) for this lane's 6 rows: one aligned
// float4 per row. Clamped so out-of-range prefetches stay valid.
__device__ __forceinline__ void load_x4(const float* __restrict__ xb, int h0, int g,
                                        float4 (&buf)[EPL]) {
    int w4 = 4 * g;
    if (w4 > WW - 4) w4 = WW - 4;
    if (w4 < 0) w4 = 0;
#pragma unroll
    for (int j = 0; j < EPL; ++j)
        buf[j] = *(const float4*)(xb + (size_t)(h0 + j) * WW + w4);
}

// ws layout per batch: column w stored as [w][j*64 + lane] -> every access is
// a fully coalesced 256B wave transaction. Layout is private to this kernel.
__device__ __forceinline__ void load_ws4(const float* __restrict__ wsb, int l, int g,
                                         float (&buf)[4][EPL]) {
    int w4 = 4 * g;
    if (w4 < 0) w4 = 0;
    if (w4 > WW - 4) w4 = WW - 4;
#pragma unroll
    for (int u = 0; u < 4; ++u)
#pragma unroll
        for (int j = 0; j < EPL; ++j)
            buf[u][j] = wsb[(size_t)(w4 + u) * HH + j * NL + l];
}

__device__ __forceinline__ float comp4(const float4& q, int u) {
    return (u == 0) ? q.x : (u == 1) ? q.y : (u == 2) ? q.z : q.w;
}

// Pass 1, 4 steps: out1[w] = x[w] + relu(conv(out1[w-1])), store to ws.
__device__ __forceinline__ void p1_group(float (&v)[EPL], const float4 (&xg)[EPL],
                                         int g, float* __restrict__ wsb, int l,
                                         const float (&wl)[KS]) {
#pragma unroll
    for (int u = 0; u < 4; ++u) {
        int w = 4 * g + u;
        if (w == 0 || w >= WW) continue;
        float a[EPL];
        conv9_relu(v, wl, a);
#pragma unroll
        for (int j = 0; j < EPL; ++j) {
            v[j] = comp4(xg[j], u) + a[j];
            wsb[(size_t)w * HH + j * NL + l] = v[j];
        }
    }
}

// Pass 2, 4 steps descending: out2[w] = out1[w] + relu(conv(out2[w+1])) -> d_out.
__device__ __forceinline__ void p2_group(float (&v)[EPL], const float (&og)[4][EPL],
                                         int g, float* __restrict__ outb, int l,
                                         const float (&wr)[KS]) {
#pragma unroll
    for (int uu = 0; uu < 4; ++uu) {
        int u = 3 - uu;
        int w = 4 * g + u;
        if ((unsigned)w >= (unsigned)(WW - 1)) continue;   // skip w=1279 and w<0
        float a[EPL];
        conv9_relu(v, wr, a);
#pragma unroll
        for (int j = 0; j < EPL; ++j) {
            v[j] = og[u][j] + a[j];
            outb[(size_t)(l * EPL + j) * WW + w] = v[j];
        }
    }
}

__global__ __launch_bounds__(NL) void scnn_scan(const float* __restrict__ x,
                                                float* __restrict__ ws,
                                                float* __restrict__ out,
                                                const float* __restrict__ w_lr,
                                                const float* __restrict__ w_rl) {
    const int b  = blockIdx.x;
    const int l  = threadIdx.x;
    const int h0 = l * EPL;
    const float* xb  = x   + (size_t)b * HH * WW;
    float*       wsb = ws  + (size_t)b * WW * HH;
    float*       outb = out + (size_t)b * HH * WW;

    float wl[KS], wr[KS];
#pragma unroll
    for (int k = 0; k < KS; ++k) { wl[k] = w_lr[k]; wr[k] = w_rl[k]; }

    float v[EPL];

    // ---------------- pass 1 (left -> right) ----------------
    {
        float4 A[EPL], B[EPL], C[EPL];
        load_x4(xb, h0, 0, A);
        load_x4(xb, h0, 1, B);
        load_x4(xb, h0, 2, C);
#pragma unroll
        for (int j = 0; j < EPL; ++j) {
            v[j] = comp4(A[j], 0);                    // out1 col 0 = x col 0
            wsb[(size_t)0 * HH + j * NL + l] = v[j];
        }
        for (int g = 0; g < 320; g += 3) {
            p1_group(v, A, g, wsb, l, wl);
            load_x4(xb, h0, g + 3, A);
            p1_group(v, B, g + 1, wsb, l, wl);
            load_x4(xb, h0, g + 4, B);
            p1_group(v, C, g + 2, wsb, l, wl);
            load_x4(xb, h0, g + 5, C);
        }
    }

    // pass-1 stores must be visible to pass-2 loads (same wave, same L2)
    asm volatile("s_waitcnt vmcnt(0)" ::: "memory");

    // ---------------- pass 2 (right -> left) ----------------
    {
        float O1[4][EPL], O2[4][EPL], O3[4][EPL];
        load_ws4(wsb, l, 319, O1);
        load_ws4(wsb, l, 318, O2);
        load_ws4(wsb, l, 317, O3);
#pragma unroll
        for (int j = 0; j < EPL; ++j)                  // out2 col W-1 = out1 col W-1
            outb[(size_t)(h0 + j) * WW + (WW - 1)] = v[j];
        for (int g = 319; g >= 1; g -= 3) {
            p2_group(v, O1, g, outb, l, wr);
            load_ws4(wsb, l, g - 3, O1);
            p2_group(v, O2, g - 1, outb, l, wr);
            load_ws4(wsb, l, g - 4, O2);
            p2_group(v, O3, g - 2, outb, l, wr);
            load_ws4(wsb, l, g - 5, O3);
        }
    }
}

extern "C" void kernel_launch(void* const* d_in, const int* in_sizes, int n_in,
                              void* d_out, int out_size, void* d_ws, size_t ws_size,
                              hipStream_t stream) {
    const float* x    = (const float*)d_in[0];
    const float* w_lr = (const float*)d_in[1];
    const float* w_rl = (const float*)d_in[2];
    float* out = (float*)d_out;
    float* ws  = (float*)d_ws;   // B*W*H floats = 62.9 MB

    scnn_scan<<<BB, NL, 0, stream>>>(x, ws, out, w_lr, w_rl);
}

// Round 3
// 453.154 us; speedup vs baseline: 1.5460x; 1.3322x over previous
//
#include <hip/hip_runtime.h>

#define BB 32
#define HH 384
#define WW 1280
#define KS 9
#define NL 64     // lanes per wave
#define EPL 6     // H elements per lane (384/64)

typedef float2 f2;
typedef float4 f4;

// DPP wave shifts: neighbor-lane exchange at VALU latency; bound_ctrl=true
// zero-fills the edge lane (free zero padding). Verified correct in round 2.
__device__ __forceinline__ float dpp_up1(float x) {   // lane i <- lane i-1; lane 0 <- 0
    return __int_as_float(__builtin_amdgcn_mov_dpp(__float_as_int(x), 0x138, 0xf, 0xf, true));
}
__device__ __forceinline__ float dpp_dn1(float x) {   // lane i <- lane i+1; lane 63 <- 0
    return __int_as_float(__builtin_amdgcn_mov_dpp(__float_as_int(x), 0x130, 0xf, 0xf, true));
}

__device__ __forceinline__ float comp4(const f4& q, int u) {
    return (u == 0) ? q.x : (u == 1) ? q.y : (u == 2) ? q.z : q.w;
}
__device__ __forceinline__ void set4(f4& q, int u, float val) {
    if (u == 0) q.x = val; else if (u == 1) q.y = val;
    else if (u == 2) q.z = val; else q.w = val;
}
__device__ __forceinline__ float getf2(const f2& q, int c) { return c ? q.y : q.x; }

// 9-tap correlation along H + ReLU. k-OUTER loop: the 6 accumulator chains
// interleave -> no dependent-FMA bubbles with a single resident wave.
__device__ __forceinline__ void conv9_relu(const float (&v)[EPL], const float (&wk)[KS],
                                           float (&a)[EPL]) {
    float n[EPL + 8];
    n[0]  = dpp_up1(v[2]);
    n[1]  = dpp_up1(v[3]);
    n[2]  = dpp_up1(v[4]);
    n[3]  = dpp_up1(v[5]);
#pragma unroll
    for (int j = 0; j < EPL; ++j) n[4 + j] = v[j];
    n[10] = dpp_dn1(v[0]);
    n[11] = dpp_dn1(v[1]);
    n[12] = dpp_dn1(v[2]);
    n[13] = dpp_dn1(v[3]);
#pragma unroll
    for (int j = 0; j < EPL; ++j) a[j] = wk[0] * n[j];
#pragma unroll
    for (int k = 1; k < KS; ++k)
#pragma unroll
        for (int j = 0; j < EPL; ++j) a[j] = fmaf(wk[k], n[j + k], a[j]);
#pragma unroll
    for (int j = 0; j < EPL; ++j) a[j] = fmaxf(a[j], 0.f);
}

// ---- pass 1: load 4 x-columns (one aligned float4 per row) ----
__device__ __forceinline__ void ldx(const float* __restrict__ xb, int h0, int g,
                                    f4 (&buf)[EPL]) {
    const float* p = xb + 4 * g;
#pragma unroll
    for (int j = 0; j < EPL; ++j)
        buf[j] = *(const f4*)(p + (size_t)(h0 + j) * WW);
}

// process 4 columns ascending; ws stores are packed f2, fully coalesced.
// colbase = ws2(batch) + lane + (4g)*192.
template<bool FIRST>
__device__ __forceinline__ void p1g(float (&v)[EPL], const f4 (&xg)[EPL],
                                    f2* __restrict__ colbase, const float (&wl)[KS]) {
#pragma unroll
    for (int u = 0; u < 4; ++u) {
        if (FIRST && u == 0) {
#pragma unroll
            for (int j = 0; j < EPL; ++j) v[j] = comp4(xg[j], 0);   // out1[0] = x[0]
        } else {
            float a[EPL];
            conv9_relu(v, wl, a);
#pragma unroll
            for (int j = 0; j < EPL; ++j) v[j] = comp4(xg[j], u) + a[j];
        }
        f2* pc = colbase + (size_t)u * (HH / 2);
        pc[0]   = make_float2(v[0], v[1]);
        pc[64]  = make_float2(v[2], v[3]);
        pc[128] = make_float2(v[4], v[5]);
    }
}

// ---- pass 2: load 4 out1-columns (3 coalesced f2 per column) ----
__device__ __forceinline__ void ldo(const f2* __restrict__ wsl, int g, f2 (&buf)[12]) {
    const f2* p = wsl + (size_t)(4 * g) * (HH / 2);
#pragma unroll
    for (int u = 0; u < 4; ++u)
#pragma unroll
        for (int k = 0; k < 3; ++k)
            buf[u * 3 + k] = p[(size_t)u * (HH / 2) + k * 64];
}

// process 4 columns DESCENDING into the 8-column register output buffer.
// cbase = 4 (high half) or 0 (low half). FIRST: col W-1 = copy of out1.
template<bool FIRST>
__device__ __forceinline__ void p2g(float (&v)[EPL], const f2 (&og)[12], int cbase,
                                    f4 (&ob)[EPL][2], const float (&wr)[KS]) {
#pragma unroll
    for (int uu = 0; uu < 4; ++uu) {
        const int u = 3 - uu;
        if (FIRST && u == 3) {
#pragma unroll
            for (int j = 0; j < EPL; ++j) v[j] = getf2(og[u * 3 + j / 2], j & 1);
        } else {
            float a[EPL];
            conv9_relu(v, wr, a);
#pragma unroll
            for (int j = 0; j < EPL; ++j)
                v[j] = getf2(og[u * 3 + j / 2], j & 1) + a[j];
        }
        const int c = cbase + u;   // 0..7 within the flush window
#pragma unroll
        for (int j = 0; j < EPL; ++j) set4(ob[j][c >> 2], c & 3, v[j]);
    }
}

// flush 8 buffered columns as float4 row segments (L2 write-combines lines)
__device__ __forceinline__ void flush8(const f4 (&ob)[EPL][2],
                                       float* __restrict__ orow, int w8) {
#pragma unroll
    for (int j = 0; j < EPL; ++j) {
        float* r = orow + (size_t)j * WW + w8;
        *(f4*)(r)     = ob[j][0];
        *(f4*)(r + 4) = ob[j][1];
    }
}

__global__ __launch_bounds__(NL) void scnn_scan(const float* __restrict__ x,
                                                float* __restrict__ ws,
                                                float* __restrict__ out,
                                                const float* __restrict__ w_lr,
                                                const float* __restrict__ w_rl) {
    const int b  = blockIdx.x;
    const int l  = threadIdx.x;
    const int h0 = l * EPL;

    const float* xb   = x   + (size_t)b * HH * WW;
    float*       outb = out + (size_t)b * HH * WW;
    f2*          ws2b = (f2*)ws + (size_t)b * WW * (HH / 2);
    f2*          wsl  = ws2b + l;
    float*       orow = outb + (size_t)h0 * WW;

    float wl[KS], wr[KS];
#pragma unroll
    for (int k = 0; k < KS; ++k) { wl[k] = w_lr[k]; wr[k] = w_rl[k]; }

    float v[EPL];

    // ================= pass 1 (left -> right) =================
    {
        f4 A[EPL], B[EPL], C[EPL], D[EPL];
        ldx(xb, h0, 0, A); ldx(xb, h0, 1, B); ldx(xb, h0, 2, C); ldx(xb, h0, 3, D);
        f2* wp = wsl;
        // peeled first block (col 0 special)
        p1g<true >(v, A, wp, wl); wp += 768; ldx(xb, h0, 4, A);
        p1g<false>(v, B, wp, wl); wp += 768; ldx(xb, h0, 5, B);
        p1g<false>(v, C, wp, wl); wp += 768; ldx(xb, h0, 6, C);
        p1g<false>(v, D, wp, wl); wp += 768; ldx(xb, h0, 7, D);
        for (int i = 1; i <= 78; ++i) {
            p1g<false>(v, A, wp, wl); wp += 768; ldx(xb, h0, 4 * i + 4, A);
            p1g<false>(v, B, wp, wl); wp += 768; ldx(xb, h0, 4 * i + 5, B);
            p1g<false>(v, C, wp, wl); wp += 768; ldx(xb, h0, 4 * i + 6, C);
            p1g<false>(v, D, wp, wl); wp += 768; ldx(xb, h0, 4 * i + 7, D);
        }
        p1g<false>(v, A, wp, wl); wp += 768;   // g=316
        p1g<false>(v, B, wp, wl); wp += 768;   // g=317
        p1g<false>(v, C, wp, wl); wp += 768;   // g=318
        p1g<false>(v, D, wp, wl);              // g=319
    }

    // pass-1 ws stores must be visible to pass-2 loads (same wave / L1 / L2)
    asm volatile("s_waitcnt vmcnt(0)" ::: "memory");

    // ================= pass 2 (right -> left) =================
    {
        f2 A[12], B[12], C[12], D[12];
        ldo(wsl, 319, A); ldo(wsl, 318, B); ldo(wsl, 317, C); ldo(wsl, 316, D);
        f4 ob[EPL][2];
        // peeled first 16 columns (col 1279 special)
        p2g<true >(v, A, 4, ob, wr); ldo(wsl, 315, A);
        p2g<false>(v, B, 0, ob, wr); ldo(wsl, 314, B);
        flush8(ob, orow, 1272);
        p2g<false>(v, C, 4, ob, wr); ldo(wsl, 313, C);
        p2g<false>(v, D, 0, ob, wr); ldo(wsl, 312, D);
        flush8(ob, orow, 1264);
        for (int i = 0; i < 78; ++i) {
            p2g<false>(v, A, 4, ob, wr); ldo(wsl, 311 - 4 * i, A);
            p2g<false>(v, B, 0, ob, wr); ldo(wsl, 310 - 4 * i, B);
            flush8(ob, orow, 1256 - 16 * i);
            p2g<false>(v, C, 4, ob, wr); ldo(wsl, 309 - 4 * i, C);
            p2g<false>(v, D, 0, ob, wr); ldo(wsl, 308 - 4 * i, D);
            flush8(ob, orow, 1248 - 16 * i);
        }
        // epilogue: groups 3..0 already resident in A..D
        p2g<false>(v, A, 4, ob, wr);           // cols 15..12
        p2g<false>(v, B, 0, ob, wr);           // cols 11..8
        flush8(ob, orow, 8);
        p2g<false>(v, C, 4, ob, wr);           // cols 7..4
        p2g<false>(v, D, 0, ob, wr);           // cols 3..0
        flush8(ob, orow, 0);
    }
}

extern "C" void kernel_launch(void* const* d_in, const int* in_sizes, int n_in,
                              void* d_out, int out_size, void* d_ws, size_t ws_size,
                              hipStream_t stream) {
    const float* x    = (const float*)d_in[0];
    const float* w_lr = (const float*)d_in[1];
    const float* w_rl = (const float*)d_in[2];
    float* out = (float*)d_out;
    float* ws  = (float*)d_ws;   // B*W*H floats = 62.9 MB scratch

    scnn_scan<<<BB, NL, 0, stream>>>(x, ws, out, w_lr, w_rl);
}

// Round 4
// 397.952 us; speedup vs baseline: 1.7604x; 1.1387x over previous
//
#include <hip/hip_runtime.h>

#define BB 32
#define HH 384
#define WW 1280
#define KS 9
#define NL 64     // lanes per wave
// lane l holds h = 6l..6l+5 as three packed float2 register pairs

typedef float f2v __attribute__((ext_vector_type(2)));
typedef float4 f4;

// DPP wave shifts: neighbor-lane exchange at VALU latency; bound_ctrl=true
// zero-fills the edge lane (free zero padding). Verified in rounds 2-3.
__device__ __forceinline__ float dpp_up1(float v) {   // lane i <- lane i-1; lane 0 <- 0
    return __int_as_float(__builtin_amdgcn_mov_dpp(__float_as_int(v), 0x138, 0xf, 0xf, true));
}
__device__ __forceinline__ float dpp_dn1(float v) {   // lane i <- lane i+1; lane 63 <- 0
    return __int_as_float(__builtin_amdgcn_mov_dpp(__float_as_int(v), 0x130, 0xf, 0xf, true));
}
__device__ __forceinline__ float comp4(const f4& q, int u) {
    return (u == 0) ? q.x : (u == 1) ? q.y : (u == 2) ? q.z : q.w;
}
__device__ __forceinline__ void set4(f4& q, int u, float val) {
    if (u == 0) q.x = val; else if (u == 1) q.y = val;
    else if (u == 2) q.z = val; else q.w = val;
}

// 9-tap correlation + ReLU on the packed column V[3] (pairs (v0,v1),(v2,v3),
// (v4,v5)). n[t] = padded p[h0-4+t]. Even taps use pair-aligned P[m]=(n2m,n2m+1),
// odd taps use Q[m]=(n2m+1,n2m+2). 27 v_pk_fma_f32 + 3 pk_mul + 3 pk_max.
__device__ __forceinline__ void conv9pk(const f2v (&V)[3], const f2v (&Wt)[KS],
                                        f2v (&A)[3]) {
    f2v P0, P1, P5, P6, Q0, Q1, Q2, Q3, Q4, Q5;
    P0.x = dpp_up1(V[1].x); P0.y = dpp_up1(V[1].y);   // (n0,n1)
    P1.x = dpp_up1(V[2].x); P1.y = dpp_up1(V[2].y);   // (n2,n3)
    P5.x = dpp_dn1(V[0].x); P5.y = dpp_dn1(V[0].y);   // (n10,n11)
    P6.x = dpp_dn1(V[1].x); P6.y = dpp_dn1(V[1].y);   // (n12,n13)
    Q0.x = P0.y;   Q0.y = P1.x;                       // (n1,n2)
    Q1.x = P1.y;   Q1.y = V[0].x;                     // (n3,n4)
    Q2.x = V[0].y; Q2.y = V[1].x;                     // (n5,n6)
    Q3.x = V[1].y; Q3.y = V[2].x;                     // (n7,n8)
    Q4.x = V[2].y; Q4.y = P5.x;                       // (n9,n10)
    Q5.x = P5.y;   Q5.y = P6.x;                       // (n11,n12)
    const f2v P[7] = {P0, P1, V[0], V[1], V[2], P5, P6};
    const f2v Q[6] = {Q0, Q1, Q2, Q3, Q4, Q5};
    const f2v zero = {0.f, 0.f};
#pragma unroll
    for (int p = 0; p < 3; ++p) {
        f2v acc = Wt[0] * P[p];
        acc = __builtin_elementwise_fma(Wt[2], P[p + 1], acc);
        acc = __builtin_elementwise_fma(Wt[4], P[p + 2], acc);
        acc = __builtin_elementwise_fma(Wt[6], P[p + 3], acc);
        acc = __builtin_elementwise_fma(Wt[8], P[p + 4], acc);
        acc = __builtin_elementwise_fma(Wt[1], Q[p + 0], acc);
        acc = __builtin_elementwise_fma(Wt[3], Q[p + 1], acc);
        acc = __builtin_elementwise_fma(Wt[5], Q[p + 2], acc);
        acc = __builtin_elementwise_fma(Wt[7], Q[p + 3], acc);
        A[p] = __builtin_elementwise_max(acc, zero);
    }
}

// x loads: uniform base + uniform (j*WW + col) + lane-fixed h0*WW -> saddr form
__device__ __forceinline__ void ldx(const float* __restrict__ xb, int h0, int col,
                                    f4 (&X)[6]) {
#pragma unroll
    for (int j = 0; j < 6; ++j)
        X[j] = *(const f4*)(xb + (size_t)(h0 + j) * WW + col);
}

// pass-1 step x4: out1[w] = x[w] + relu(conv(out1[w-1])); store packed pairs to
// the 3 planar ws buffers (plane p holds pair p of every column, [w][lane]).
template<bool FIRST>
__device__ __forceinline__ void p1g(f2v (&V)[3], const f4 (&X)[6], const f2v (&Wl)[KS],
                                    f2v* __restrict__ pl0, f2v* __restrict__ pl1,
                                    f2v* __restrict__ pl2, int l, int w0) {
#pragma unroll
    for (int u = 0; u < 4; ++u) {
        if (FIRST && u == 0) {
            f2v t0, t1, t2;
            t0.x = X[0].x; t0.y = X[1].x;
            t1.x = X[2].x; t1.y = X[3].x;
            t2.x = X[4].x; t2.y = X[5].x;
            V[0] = t0; V[1] = t1; V[2] = t2;
        } else {
            f2v A[3];
            conv9pk(V, Wl, A);
            f2v t0, t1, t2;
            t0.x = comp4(X[0], u) + A[0].x;  t0.y = comp4(X[1], u) + A[0].y;
            t1.x = comp4(X[2], u) + A[1].x;  t1.y = comp4(X[3], u) + A[1].y;
            t2.x = comp4(X[4], u) + A[2].x;  t2.y = comp4(X[5], u) + A[2].y;
            V[0] = t0; V[1] = t1; V[2] = t2;
        }
        const size_t o = (size_t)(w0 + u) * NL + l;
        pl0[o] = V[0]; pl1[o] = V[1]; pl2[o] = V[2];
    }
}

// pass-2 loads: 4 columns of out1 pairs from the planar ws
__device__ __forceinline__ void ldo(const f2v* __restrict__ pl0,
                                    const f2v* __restrict__ pl1,
                                    const f2v* __restrict__ pl2,
                                    int l, int w0, f2v (&OG)[4][3]) {
#pragma unroll
    for (int u = 0; u < 4; ++u) {
        const size_t o = (size_t)(w0 + u) * NL + l;
        OG[u][0] = pl0[o]; OG[u][1] = pl1[o]; OG[u][2] = pl2[o];
    }
}

// pass-2 step x4 descending: out2[w] = out1[w] + relu(conv(out2[w+1])), into
// the 8-column register output window (cbase = 4 for high half, 0 for low).
template<bool FIRST>
__device__ __forceinline__ void p2g(f2v (&V)[3], const f2v (&OG)[4][3], int cbase,
                                    f4 (&ob)[6][2], const f2v (&Wr)[KS]) {
#pragma unroll
    for (int uu = 0; uu < 4; ++uu) {
        const int u = 3 - uu;
        if (FIRST && u == 3) {
            V[0] = OG[3][0]; V[1] = OG[3][1]; V[2] = OG[3][2];
        } else {
            f2v A[3];
            conv9pk(V, Wr, A);
            V[0] = OG[u][0] + A[0];     // v_pk_add_f32
            V[1] = OG[u][1] + A[1];
            V[2] = OG[u][2] + A[2];
        }
        const int c = cbase + u;
        set4(ob[0][c >> 2], c & 3, V[0].x);
        set4(ob[1][c >> 2], c & 3, V[0].y);
        set4(ob[2][c >> 2], c & 3, V[1].x);
        set4(ob[3][c >> 2], c & 3, V[1].y);
        set4(ob[4][c >> 2], c & 3, V[2].x);
        set4(ob[5][c >> 2], c & 3, V[2].y);
    }
}

// flush 8 buffered columns as two float4 row segments per h-row
__device__ __forceinline__ void flush8(const f4 (&ob)[6][2], float* __restrict__ outb,
                                       int h0, int w8) {
#pragma unroll
    for (int j = 0; j < 6; ++j) {
        *(f4*)(outb + (size_t)(h0 + j) * WW + w8)     = ob[j][0];
        *(f4*)(outb + (size_t)(h0 + j) * WW + w8 + 4) = ob[j][1];
    }
}

__global__ __launch_bounds__(NL, 1) void scnn_scan(const float* __restrict__ x,
                                                   float* __restrict__ ws,
                                                   float* __restrict__ out,
                                                   const float* __restrict__ w_lr,
                                                   const float* __restrict__ w_rl) {
    const int b  = blockIdx.x;
    const int l  = threadIdx.x;
    const int h0 = l * 6;

    const float* xb   = x   + (size_t)b * HH * WW;
    float*       outb = out + (size_t)b * HH * WW;
    f2v* wsv = (f2v*)ws;
    f2v* pl0 = wsv + (size_t)(0 * BB + b) * WW * NL;
    f2v* pl1 = wsv + (size_t)(1 * BB + b) * WW * NL;
    f2v* pl2 = wsv + (size_t)(2 * BB + b) * WW * NL;

    f2v Wl[KS], Wr[KS];
#pragma unroll
    for (int k = 0; k < KS; ++k) {
        const float a = w_lr[k], c = w_rl[k];
        f2v ta, tc;
        ta.x = a; ta.y = a;  tc.x = c; tc.y = c;
        Wl[k] = ta; Wr[k] = tc;
    }

    f2v V[3];

    // ================= pass 1 (left -> right) =================
    {
        f4 XA[6], XB[6], XC[6], XD[6];
        ldx(xb, h0, 0, XA); ldx(xb, h0, 4, XB); ldx(xb, h0, 8, XC); ldx(xb, h0, 12, XD);
        // macro-iter 0 peeled (col 0 special)
        p1g<true >(V, XA, Wl, pl0, pl1, pl2, l, 0);  ldx(xb, h0, 16, XA);
        p1g<false>(V, XB, Wl, pl0, pl1, pl2, l, 4);  ldx(xb, h0, 20, XB);
        p1g<false>(V, XC, Wl, pl0, pl1, pl2, l, 8);  ldx(xb, h0, 24, XC);
        p1g<false>(V, XD, Wl, pl0, pl1, pl2, l, 12); ldx(xb, h0, 28, XD);
#pragma unroll 1
        for (int m = 1; m < 79; ++m) {
            const int c0 = 16 * m;
            p1g<false>(V, XA, Wl, pl0, pl1, pl2, l, c0 + 0);  ldx(xb, h0, c0 + 16, XA);
            p1g<false>(V, XB, Wl, pl0, pl1, pl2, l, c0 + 4);  ldx(xb, h0, c0 + 20, XB);
            p1g<false>(V, XC, Wl, pl0, pl1, pl2, l, c0 + 8);  ldx(xb, h0, c0 + 24, XC);
            p1g<false>(V, XD, Wl, pl0, pl1, pl2, l, c0 + 12); ldx(xb, h0, c0 + 28, XD);
        }
        // epilogue: cols 1264..1279, no prefetch
        p1g<false>(V, XA, Wl, pl0, pl1, pl2, l, 1264);
        p1g<false>(V, XB, Wl, pl0, pl1, pl2, l, 1268);
        p1g<false>(V, XC, Wl, pl0, pl1, pl2, l, 1272);
        p1g<false>(V, XD, Wl, pl0, pl1, pl2, l, 1276);
    }

    // pass-1 ws stores must be retired before pass-2 reads them back
    asm volatile("s_waitcnt vmcnt(0)" ::: "memory");

    // ================= pass 2 (right -> left) =================
    {
        f2v GA[4][3], GB[4][3], GC[4][3], GD[4][3];
        ldo(pl0, pl1, pl2, l, 1276, GA);
        ldo(pl0, pl1, pl2, l, 1272, GB);
        ldo(pl0, pl1, pl2, l, 1268, GC);
        ldo(pl0, pl1, pl2, l, 1264, GD);
        f4 ob[6][2];
        // macro-iter 0 peeled (col 1279 special)
        p2g<true >(V, GA, 4, ob, Wr); ldo(pl0, pl1, pl2, l, 1260, GA);
        p2g<false>(V, GB, 0, ob, Wr); ldo(pl0, pl1, pl2, l, 1256, GB);
        flush8(ob, outb, h0, 1272);
        p2g<false>(V, GC, 4, ob, Wr); ldo(pl0, pl1, pl2, l, 1252, GC);
        p2g<false>(V, GD, 0, ob, Wr); ldo(pl0, pl1, pl2, l, 1248, GD);
        flush8(ob, outb, h0, 1264);
#pragma unroll 1
        for (int t = 1; t < 79; ++t) {
            const int cA = 1276 - 16 * t;    // column base of buffer A this iter
            p2g<false>(V, GA, 4, ob, Wr); ldo(pl0, pl1, pl2, l, cA - 16, GA);
            p2g<false>(V, GB, 0, ob, Wr); ldo(pl0, pl1, pl2, l, cA - 20, GB);
            flush8(ob, outb, h0, cA - 4);
            p2g<false>(V, GC, 4, ob, Wr); ldo(pl0, pl1, pl2, l, cA - 24, GC);
            p2g<false>(V, GD, 0, ob, Wr); ldo(pl0, pl1, pl2, l, cA - 28, GD);
            flush8(ob, outb, h0, cA - 12);
        }
        // epilogue: cols 15..0, no prefetch
        p2g<false>(V, GA, 4, ob, Wr);
        p2g<false>(V, GB, 0, ob, Wr);
        flush8(ob, outb, h0, 8);
        p2g<false>(V, GC, 4, ob, Wr);
        p2g<false>(V, GD, 0, ob, Wr);
        flush8(ob, outb, h0, 0);
    }
}

extern "C" void kernel_launch(void* const* d_in, const int* in_sizes, int n_in,
                              void* d_out, int out_size, void* d_ws, size_t ws_size,
                              hipStream_t stream) {
    const float* x    = (const float*)d_in[0];
    const float* w_lr = (const float*)d_in[1];
    const float* w_rl = (const float*)d_in[2];
    float* out = (float*)d_out;
    float* ws  = (float*)d_ws;   // 3 planes * 32 * 1280 * 64 f2v = 62.9 MB

    scnn_scan<<<BB, NL, 0, stream>>>(x, ws, out, w_lr, w_rl);
}